// Round 7
// baseline (84.004 us; speedup 1.0000x reference)
//
#include <hip/hip_runtime.h>

// OIM unsupervised loss, MI355X/gfx950 — round 7.
// 256x256 tile, 8 waves (2M x 4N, per-wave 128x64), f16 K=256,
// mfma_f32_16x16x32_f16 swapped-operand (lane-local output rows).
// K-loop: BK=32, 8 K-tiles, TRIPLE-buffered LDS (96KB), counted vmcnt(4)
// per tile (vmcnt(0) only at the last), one barrier per tile, stage of
// tile t+2 issued after tile t's barrier (race-free: that buffer was last
// read at tile t-1). 1 block/CU; intra-block pipeline carries the overlap.

#define BT 4096
#define NPID 5000
#define FDIM 256
#define NCHUNK 8         // FDIM / 32
#define BPROWS 10240
#define SIDE 5120
#define SCALE2 43.2808512266689f   // 30*log2(e)
#define LN2 0.6931471805599453f
#define PADMARK ((int)0x80000000)

typedef __attribute__((ext_vector_type(8))) _Float16 half8;
typedef __attribute__((ext_vector_type(4))) float f32x4;

// 16B-unit index of (row, oct) in 16x16x32 fragment-linear layout.
// frag-block = 16 rows x 32 k = 1KB; lane = (row&15) + 16*(k>>3).
__device__ __forceinline__ size_t frag_unit(int row, int oct) {
  int c  = oct >> 2;   // 32-wide k-chunk (0..7)
  int ko = oct & 3;    // 8-wide oct within chunk
  return ((size_t)(row >> 4) * NCHUNK + c) * 64 + (row & 15) + (ko << 4);
}

__global__ __launch_bounds__(256) void convert_A(const float* __restrict__ x,
                                                 _Float16* __restrict__ outp) {
  int idx = blockIdx.x * 256 + threadIdx.x;
  if (idx >= BT * 32) return;
  int row = idx >> 5, oct = idx & 31;
  const float4* s4 = (const float4*)(x + (size_t)row * FDIM + oct * 8);
  float4 f0 = s4[0], f1 = s4[1];
  float fv[8] = {f0.x, f0.y, f0.z, f0.w, f1.x, f1.y, f1.z, f1.w};
  half8 ov;
#pragma unroll
  for (int j = 0; j < 8; ++j) ov[j] = (_Float16)fv[j];
  *(half8*)(outp + frag_unit(row, oct) * 8) = ov;
}

__global__ __launch_bounds__(256) void convert_B(const float* __restrict__ lut,
                                                 const float* __restrict__ reid,
                                                 _Float16* __restrict__ outp) {
  int idx = blockIdx.x * 256 + threadIdx.x;
  if (idx >= BPROWS * 32) return;
  int row = idx >> 5, oct = idx & 31;
  const float* src = nullptr;
  if (row < NPID) src = lut + (size_t)row * FDIM + oct * 8;
  else if (row >= SIDE && row < SIDE + NPID) src = reid + (size_t)(row - SIDE) * FDIM + oct * 8;
  half8 ov;
  if (src) {
    const float4* s4 = (const float4*)src;
    float4 f0 = s4[0], f1 = s4[1];
    float fv[8] = {f0.x, f0.y, f0.z, f0.w, f1.x, f1.y, f1.z, f1.w};
#pragma unroll
    for (int j = 0; j < 8; ++j) ov[j] = (_Float16)fv[j];
  } else {
#pragma unroll
    for (int j = 0; j < 8; ++j) ov[j] = (_Float16)0.f;
  }
  *(half8*)(outp + frag_unit(row, oct) * 8) = ov;
}

__global__ __launch_bounds__(256) void meta_fc(const float* __restrict__ inputs,
                                               const int* __restrict__ roi,
                                               const float* __restrict__ lut,
                                               const int* __restrict__ rlab,
                                               int* __restrict__ g, int* __restrict__ lr,
                                               float* __restrict__ w2f, float* __restrict__ v1f,
                                               float* __restrict__ fc) {
  int gt = blockIdx.x * 256 + threadIdx.x;
  int row = gt >> 6, lane = gt & 63;
  if (row >= BT) return;
  int t = roi[row] - 1;
  bool valid = t >= 0;
  int label = t > 0 ? t : 0;
  int gg = rlab[label];
  const float4* xv = (const float4*)(inputs + (size_t)row * FDIM);
  const float4* lv = (const float4*)(lut + (size_t)label * FDIM);
  float4 a = xv[lane], b = lv[lane];
  float dx = b.x - a.x, dy = b.y - a.y, dz = b.z - a.z, dw = b.w - a.w;
  float s = dx * dx + dy * dy + dz * dz + dw * dw;
#pragma unroll
  for (int d = 1; d < 64; d <<= 1) s += __shfl_xor(s, d, 64);
  if (lane == 0) {
    g[row]   = gg;
    lr[row]  = gg > 0 ? gg : 0;
    w2f[row] = (valid && gg >= 0) ? 1.0f : 0.0f;
    v1f[row] = valid ? 1.0f : 0.0f;
    fc[row]  = valid ? s : 0.0f;
  }
}

__global__ __launch_bounds__(512, 2) void gemm_main(const _Float16* __restrict__ Ap,
                                                    const _Float16* __restrict__ Bp,
                                                    const int* __restrict__ rlab,
                                                    const int* __restrict__ g,
                                                    const int* __restrict__ lr,
                                                    float* __restrict__ partials,
                                                    float* __restrict__ posbuf,
                                                    int* __restrict__ poscnt,
                                                    float* __restrict__ target) {
  __shared__ char smem[98304] __attribute__((aligned(16)));  // 3 x 32KB K-tile bufs
  // 640 blocks = 8 xcd * (20 cb * 2 rbl): A-panels L2-hot per XCD, B streamed once.
  const int bid = blockIdx.x;
  const int xcd = bid & 7;
  const int i   = bid >> 3;
  const int cb  = i >> 1;              // 0..39 (0..19 inst, 20..39 reid)
  const int rb  = xcd * 2 + (i & 1);   // 0..15
  const int tid = threadIdx.x;
  const int l = tid & 63;
  const int w = tid >> 6;              // 0..7
  const int wm = w >> 2, wn = w & 3;   // 2M x 4N

  // acc[mc][nr] = C^T frags (swapped operands). Lane: out row = nr*16+(l&15)
  // (+ wm*128 + rb*256), out cols = wn*64 + mc*16 + (l>>4)*4 + reg.
  f32x4 acc[4][8];
#pragma unroll
  for (int mi = 0; mi < 4; ++mi)
#pragma unroll
    for (int ni = 0; ni < 8; ++ni) acc[mi][ni] = (f32x4){0.f, 0.f, 0.f, 0.f};

  // stage K-tile t into buffer b: 32 frag-blocks of 1KB (A 16 + B 16), 4/wave.
  auto stage = [&](int t, int b) {
#pragma unroll
    for (int q = 0; q < 4; ++q) {
      const int f = w * 4 + q;
      const bool isA = f < 16;
      const int fr = isA ? f : f - 16;
      const int gfr = (isA ? rb : cb) * 16 + fr;
      const _Float16* src = (isA ? Ap : Bp) + ((size_t)gfr * NCHUNK + t) * 512 + l * 8;
      char* dst = smem + b * 32768 + (isA ? 0 : 16384) + fr * 1024;
      __builtin_amdgcn_global_load_lds(
          (const __attribute__((address_space(1))) unsigned int*)src,
          (__attribute__((address_space(3))) unsigned int*)dst, 16, 0, 0);
    }
  };

  stage(0, 0);
  stage(1, 1);                          // 8 loads/wave outstanding
#pragma unroll
  for (int t = 0; t < 8; ++t) {
    if (t < 7) asm volatile("s_waitcnt vmcnt(4)" ::: "memory");   // tile t landed
    else       asm volatile("s_waitcnt vmcnt(0)" ::: "memory");
    asm volatile("s_barrier" ::: "memory");   // all waves' tile-t loads visible;
                                              // all waves done reading tile t-1
    if (t < 6) stage(t + 2, (t + 2) % 3);     // buf last read at t-1 -> free
    const char* bb = smem + (t % 3) * 32768;
    half8 bf[4];
#pragma unroll
    for (int mc = 0; mc < 4; ++mc)
      bf[mc] = *(const half8*)(bb + 16384 + (wn * 4 + mc) * 1024 + l * 16);
#pragma unroll
    for (int ph = 0; ph < 2; ++ph) {
      half8 af[4];
#pragma unroll
      for (int j = 0; j < 4; ++j)
        af[j] = *(const half8*)(bb + (wm * 8 + ph * 4 + j) * 1024 + l * 16);
#pragma unroll
      for (int mc = 0; mc < 4; ++mc)
#pragma unroll
        for (int j = 0; j < 4; ++j)
          acc[mc][ph * 4 + j] = __builtin_amdgcn_mfma_f32_16x16x32_f16(bf[mc], af[j], acc[mc][ph * 4 + j], 0, 0, 0);
    }
  }

  // ---- epilogue: lane-local row sums, 2 shfl per row ----
  const bool inst = cb < 20;
  const int cbl = inst ? cb : cb - 20;
  __syncthreads();                      // all waves out of the K-loop
  int* rl_s = (int*)smem;               // 256 ints
  if (tid < 256) {
    int scol = cbl * 256 + tid;
    rl_s[tid] = (inst && scol < NPID) ? rlab[scol] : PADMARK;
  }
  __syncthreads();

  const int colg = l >> 4;              // 0..3
  const int rlane = l & 15;
  int4 rlv[4];
#pragma unroll
  for (int mc = 0; mc < 4; ++mc)        // broadcast reads, conflict-free
    rlv[mc] = *(const int4*)&rl_s[wn * 64 + mc * 16 + colg * 4];

  const int chunk = (inst ? 0 : 80) + cbl * 4 + wn;
  const int rowb = rb * 256 + wm * 128 + rlane;

#pragma unroll
  for (int nr = 0; nr < 8; ++nr) {
    const int row = rowb + nr * 16;
    float s = 0.f;
    if (inst) {
      const int gv = g[row];
#pragma unroll
      for (int mc = 0; mc < 4; ++mc)
#pragma unroll
        for (int reg = 0; reg < 4; ++reg) {
          float x2 = acc[mc][nr][reg] * SCALE2;
          int rl = ((const int*)&rlv[mc])[reg];
          bool pos = (rl == gv);
          if (pos) {
            int idx = atomicAdd(&poscnt[row], 1);
            if (idx < 16) posbuf[row * 16 + idx] = x2;
          }
          if (!pos && rl != PADMARK) s += exp2f(x2);
        }
    } else {
      const int lrv = lr[row];
      const int sbase = cbl * 256 + wn * 64 + colg * 4;
#pragma unroll
      for (int mc = 0; mc < 4; ++mc)
#pragma unroll
        for (int reg = 0; reg < 4; ++reg) {
          int scol = sbase + mc * 16 + reg;
          float x2 = acc[mc][nr][reg] * SCALE2;
          if (scol == lrv) target[row] = x2;
          if (scol < NPID) s += exp2f(x2);
        }
    }
    s += __shfl_xor(s, 16, 64);
    s += __shfl_xor(s, 32, 64);
    if (colg == 0) partials[(size_t)chunk * BT + row] = s;
  }
}

__global__ __launch_bounds__(256) void combine(const float* __restrict__ partials,
                                               const float* __restrict__ posbuf,
                                               const int* __restrict__ poscnt,
                                               const float* __restrict__ target,
                                               const float* __restrict__ w2f,
                                               float* __restrict__ Lrow,
                                               float* __restrict__ Crow) {
  int row = blockIdx.x * 256 + threadIdx.x;
  if (row >= BT) return;
  float S = 0.f;
  for (int i = 0; i < 80; ++i) S += partials[(size_t)i * BT + row];
  float lse2n = __log2f(S);                 // base-2 lse of negatives
  int cnt = poscnt[row];
  int cc = cnt < 16 ? cnt : 16;
  float sum = 0.f;
  for (int j = 0; j < cc; ++j) {
    float d = LN2 * (lse2n - posbuf[row * 16 + j]);
    sum += (d > 60.f) ? d : log1pf(__expf(d));
  }
  float w2 = w2f[row];
  Lrow[row] = w2 * (sum / fmaxf((float)cnt, 1.0f));
  float S2 = 0.f;
  for (int i = 80; i < 160; ++i) S2 += partials[(size_t)i * BT + row];
  Crow[row] = w2 * LN2 * (__log2f(S2) - target[row]);
}

__global__ __launch_bounds__(256) void finalize(const float* __restrict__ fc,
                                                const float* __restrict__ v1f,
                                                const float* __restrict__ w2f,
                                                const float* __restrict__ Lrow,
                                                const float* __restrict__ Crow,
                                                float* __restrict__ out) {
  int t = threadIdx.x;
  float s0 = 0, s1 = 0, s2 = 0, s3 = 0, s4 = 0;
  for (int r = t; r < BT; r += 256) {
    s0 += fc[r]; s1 += v1f[r]; s2 += w2f[r]; s3 += Lrow[r]; s4 += Crow[r];
  }
#pragma unroll
  for (int d = 1; d < 64; d <<= 1) {
    s0 += __shfl_xor(s0, d, 64);
    s1 += __shfl_xor(s1, d, 64);
    s2 += __shfl_xor(s2, d, 64);
    s3 += __shfl_xor(s3, d, 64);
    s4 += __shfl_xor(s4, d, 64);
  }
  __shared__ float red[4][5];
  int lane = t & 63, wv = t >> 6;
  if (lane == 0) { red[wv][0] = s0; red[wv][1] = s1; red[wv][2] = s2; red[wv][3] = s3; red[wv][4] = s4; }
  __syncthreads();
  if (t == 0) {
    float a0 = 0, a1 = 0, a2 = 0, a3 = 0, a4 = 0;
    for (int i = 0; i < 4; ++i) { a0 += red[i][0]; a1 += red[i][1]; a2 += red[i][2]; a3 += red[i][3]; a4 += red[i][4]; }
    float n1 = fmaxf(a1, 1.0f);
    float n2 = fmaxf(a2, 1.0f);
    out[0] = a0 / (n1 * (float)FDIM) + a4 / n2 + a3 / n2;
  }
}

extern "C" void kernel_launch(void* const* d_in, const int* in_sizes, int n_in,
                              void* d_out, int out_size, void* d_ws, size_t ws_size,
                              hipStream_t stream) {
  const float* inputs = (const float*)d_in[0];
  const int*   roi    = (const int*)d_in[1];
  const float* lut    = (const float*)d_in[2];
  const float* reid   = (const float*)d_in[3];
  const int*   rlab   = (const int*)d_in[4];
  float* out = (float*)d_out;

  char* w = (char*)d_ws;
  _Float16* Ap    = (_Float16*)(w);                  // 2,097,152 B
  _Float16* Bp    = (_Float16*)(w + 2097152);        // 5,242,880 B  -> 7,340,032
  float* partials = (float*)(w + 7340032);           // 2,621,440 B  -> 9,961,472
  float* posbuf   = (float*)(w + 9961472);           // 262,144 B    -> 10,223,616
  int*   poscnt   = (int*)(w + 10223616);            // 16,384 B     -> 10,240,000
  float* target   = (float*)(w + 10240000);          // 16,384 B     -> 10,256,384
  int*   g        = (int*)(w + 10256384);            // 16,384 B     -> 10,272,768
  int*   lr       = (int*)(w + 10272768);            // 16,384 B     -> 10,289,152
  float* w2f      = (float*)(w + 10289152);          // 16,384 B     -> 10,305,536
  float* v1f      = (float*)(w + 10305536);          // 16,384 B     -> 10,321,920
  float* fc       = (float*)(w + 10321920);          // 16,384 B     -> 10,338,304
  float* Lrow     = (float*)(w + 10338304);          // 16,384 B     -> 10,354,688
  float* Crow     = (float*)(w + 10354688);          // 16,384 B     -> 10,371,072

  hipMemsetAsync(poscnt, 0, BT * sizeof(int), stream);
  convert_A<<<(BT * 32 + 255) / 256, 256, 0, stream>>>(inputs, Ap);
  convert_B<<<(BPROWS * 32 + 255) / 256, 256, 0, stream>>>(lut, reid, Bp);
  meta_fc<<<(BT * 64) / 256, 256, 0, stream>>>(inputs, roi, lut, rlab, g, lr, w2f, v1f, fc);
  gemm_main<<<640, 512, 0, stream>>>(Ap, Bp, rlab, g, lr, partials, posbuf, poscnt, target);
  combine<<<BT / 256, 256, 0, stream>>>(partials, posbuf, poscnt, target, w2f, Lrow, Crow);
  finalize<<<1, 256, 0, stream>>>(fc, v1f, w2f, Lrow, Crow, out);
}

// Round 8
// 60.452 us; speedup vs baseline: 1.3896x; 1.3896x over previous
//
#include <hip/hip_runtime.h>

// OIM unsupervised loss, MI355X/gfx950 — round 8.
// R6 gemm structure (proven 57us) with: A pre-scaled by 30*log2(e) in prep,
// branch-free -inf exclusion + raw v_exp_f32 epilogue, rl_s/g/lr hoisted to
// the prologue (separate LDS region; loop barriers cover visibility).
// Launch fusion: prep (convert_A+convert_B+meta_fc+zeroing) and
// combine (+finalize via int64 fixed-point atomics + last-block-out). 3 launches.

#define BT 4096
#define NPID 5000
#define FDIM 256
#define NCHUNK 8         // FDIM / 32
#define BPROWS 10240
#define SIDE 5120
#define SCALE2 43.2808512266689f   // 30*log2(e)
#define LN2 0.6931471805599453f
#define PADMARK ((int)0x80000000)
#define FXS 67108864.0             // 2^26 fixed-point scale

typedef __attribute__((ext_vector_type(8))) _Float16 half8;
typedef __attribute__((ext_vector_type(4))) float f32x4;

#if __has_builtin(__builtin_amdgcn_exp2f)
#define EXP2R(x) __builtin_amdgcn_exp2f(x)
#else
#define EXP2R(x) exp2f(x)
#endif

// 16B-unit index of (row, oct) in 16x16x32 fragment-linear layout.
// frag-block = 16 rows x 32 k = 1KB; lane = (row&15) + 16*(k>>3).
__device__ __forceinline__ size_t frag_unit(int row, int oct) {
  int c  = oct >> 2;   // 32-wide k-chunk (0..7)
  int ko = oct & 3;    // 8-wide oct within chunk
  return ((size_t)(row >> 4) * NCHUNK + c) * 64 + (row & 15) + (ko << 4);
}

// prep: blockIdx ranges -> convert_A (prescaled) | convert_B | meta_fc | zeroing
__global__ __launch_bounds__(256) void prep(const float* __restrict__ inputs,
                                            const int* __restrict__ roi,
                                            const float* __restrict__ lut,
                                            const float* __restrict__ reid,
                                            const int* __restrict__ rlab,
                                            _Float16* __restrict__ Ap,
                                            _Float16* __restrict__ Bp,
                                            int* __restrict__ g, int* __restrict__ lr,
                                            float* __restrict__ w2f, float* __restrict__ v1f,
                                            float* __restrict__ fcv,
                                            int* __restrict__ poscnt,
                                            unsigned long long* __restrict__ ctrl) {
  const int b = blockIdx.x, tid = threadIdx.x;
  if (b < 512) {                       // ---- convert_A (x SCALE2) ----
    int idx = b * 256 + tid;           // 131072 = 4096*32
    int row = idx >> 5, oct = idx & 31;
    const float4* s4 = (const float4*)(inputs + (size_t)row * FDIM + oct * 8);
    float4 f0 = s4[0], f1 = s4[1];
    float fv[8] = {f0.x, f0.y, f0.z, f0.w, f1.x, f1.y, f1.z, f1.w};
    half8 ov;
#pragma unroll
    for (int j = 0; j < 8; ++j) ov[j] = (_Float16)(fv[j] * SCALE2);
    *(half8*)(Ap + frag_unit(row, oct) * 8) = ov;
  } else if (b < 1792) {               // ---- convert_B ----
    int idx = (b - 512) * 256 + tid;   // 327680 = 10240*32
    int row = idx >> 5, oct = idx & 31;
    const float* src = nullptr;
    if (row < NPID) src = lut + (size_t)row * FDIM + oct * 8;
    else if (row >= SIDE && row < SIDE + NPID) src = reid + (size_t)(row - SIDE) * FDIM + oct * 8;
    half8 ov;
    if (src) {
      const float4* s4 = (const float4*)src;
      float4 f0 = s4[0], f1 = s4[1];
      float fv[8] = {f0.x, f0.y, f0.z, f0.w, f1.x, f1.y, f1.z, f1.w};
#pragma unroll
      for (int j = 0; j < 8; ++j) ov[j] = (_Float16)fv[j];
    } else {
#pragma unroll
      for (int j = 0; j < 8; ++j) ov[j] = (_Float16)0.f;
    }
    *(half8*)(Bp + frag_unit(row, oct) * 8) = ov;
  } else if (b < 2816) {               // ---- meta_fc ----
    int gt = (b - 1792) * 256 + tid;   // 262144 = 4096*64
    int row = gt >> 6, lane = gt & 63;
    int t = roi[row] - 1;
    bool valid = t >= 0;
    int label = t > 0 ? t : 0;
    int gg = rlab[label];
    const float4* xv = (const float4*)(inputs + (size_t)row * FDIM);
    const float4* lv = (const float4*)(lut + (size_t)label * FDIM);
    float4 a = xv[lane], bb = lv[lane];
    float dx = bb.x - a.x, dy = bb.y - a.y, dz = bb.z - a.z, dw = bb.w - a.w;
    float s = dx * dx + dy * dy + dz * dz + dw * dw;
#pragma unroll
    for (int d = 1; d < 64; d <<= 1) s += __shfl_xor(s, d, 64);
    if (lane == 0) {
      g[row]   = gg;
      lr[row]  = gg > 0 ? gg : 0;
      w2f[row] = (valid && gg >= 0) ? 1.0f : 0.0f;
      v1f[row] = valid ? 1.0f : 0.0f;
      fcv[row] = valid ? s : 0.0f;
    }
  } else {                             // ---- zeroing ----
    int idx = (b - 2816) * 256 + tid;  // 4096
    poscnt[idx] = 0;
    if (b == 2816 && tid < 8) ctrl[tid] = 0ULL;
  }
}

__global__ __launch_bounds__(256, 3) void gemm_main(const _Float16* __restrict__ Ap,
                                                    const _Float16* __restrict__ Bp,
                                                    const int* __restrict__ rlab,
                                                    const int* __restrict__ g,
                                                    const int* __restrict__ lr,
                                                    float* __restrict__ partials,
                                                    float* __restrict__ posbuf,
                                                    int* __restrict__ poscnt,
                                                    float* __restrict__ target) {
  __shared__ unsigned short lds[16640] __attribute__((aligned(16)));  // 32KB ops + 512B rl_s
  // XCD-bijective, rb-fast swizzle: 2560 = 8 xcd * (80 cb * 4 rbl).
  const int bid = blockIdx.x;
  const int xcd = bid & 7;
  const int i   = bid >> 3;
  const int cb  = i >> 2;              // 0..79 (0..39 inst, 40..79 reid)
  const int rb  = xcd * 4 + (i & 3);   // 0..31
  const int tid = threadIdx.x;
  const int l = tid & 63;
  const int w = tid >> 6;
  const int wr = w >> 1, wc = w & 1;

  const bool inst = cb < 40;
  const int cbl = inst ? cb : cb - 40;

  // ---- prologue: stage rl_s (separate LDS region; K-loop barriers cover it),
  //      preload per-row keys (latency hidden under the whole K-loop) ----
  int* rl_s = (int*)&lds[16384];
  if (tid < 128) {
    int scol = cbl * 128 + tid;
    rl_s[tid] = (inst && scol < NPID) ? rlab[scol] : PADMARK;
  }
  const int rlane = l & 15;
  const int rowb = rb * 128 + wr * 64 + rlane;
  int key[4];
#pragma unroll
  for (int nr = 0; nr < 4; ++nr)
    key[nr] = inst ? g[rowb + nr * 16] : lr[rowb + nr * 16];

  // acc[mc][nr]: C^T fragments (swapped operands). Lane: out row = nr*16+rlane,
  // out cols = wc*64 + mc*16 + (l>>4)*4 + reg.
  f32x4 acc[4][4];
#pragma unroll
  for (int mi = 0; mi < 4; ++mi)
#pragma unroll
    for (int ni = 0; ni < 4; ++ni) acc[mi][ni] = (f32x4){0.f, 0.f, 0.f, 0.f};

  for (int s = 0; s < 4; ++s) {            // K-steps of 64 (2 mfma chunks)
    const int c0 = s * 2;
    __syncthreads();
#pragma unroll
    for (int q = 0; q < 8; ++q) {          // 32 frag-blocks of 1KB, 8 per wave
      const int f = w * 8 + q;
      const bool isA = f < 16;
      const int fl = isA ? f : f - 16;
      const int cc = fl >> 3;
      const int grp = fl & 7;
      const int gidx = isA ? (rb * 8 + grp) : (cb * 8 + grp);
      const _Float16* src = (isA ? Ap : Bp)
          + (((size_t)gidx * NCHUNK + (c0 + cc)) << 6) * 8 + l * 8;
      unsigned short* dst = &lds[f * 512];
      __builtin_amdgcn_global_load_lds((const __attribute__((address_space(1))) unsigned int*)src,
                                       (__attribute__((address_space(3))) unsigned int*)dst,
                                       16, 0, 0);
    }
    __syncthreads();
#pragma unroll
    for (int cc = 0; cc < 2; ++cc) {
      half8 cf[4], rf[4];
#pragma unroll
      for (int mc = 0; mc < 4; ++mc)       // col-frags from B region
        cf[mc] = *(const half8*)&lds[8192 + (cc * 8 + (wc * 4 + mc)) * 512 + l * 8];
#pragma unroll
      for (int nr = 0; nr < 4; ++nr)       // row-frags from A region
        rf[nr] = *(const half8*)&lds[(cc * 8 + (wr * 4 + nr)) * 512 + l * 8];
#pragma unroll
      for (int mc = 0; mc < 4; ++mc)
#pragma unroll
        for (int nr = 0; nr < 4; ++nr)
          acc[mc][nr] = __builtin_amdgcn_mfma_f32_16x16x32_f16(cf[mc], rf[nr], acc[mc][nr], 0, 0, 0);
    }
  }

  // ---- epilogue: lane-local row sums, branch-free -inf exclusion, raw exp2 ----
  const int colg = l >> 4;                  // 0..3
  int4 rlv[4];
#pragma unroll
  for (int mc = 0; mc < 4; ++mc)            // broadcast reads, conflict-free
    rlv[mc] = *(const int4*)&rl_s[wc * 64 + mc * 16 + colg * 4];

  const int chunk = (inst ? 0 : 80) + cbl * 2 + wc;
  const float NINF = -__builtin_inff();

#pragma unroll
  for (int nr = 0; nr < 4; ++nr) {
    const int row = rowb + nr * 16;
    const int kv = key[nr];
    float s = 0.f;
    if (inst) {
#pragma unroll
      for (int mc = 0; mc < 4; ++mc)
#pragma unroll
        for (int reg = 0; reg < 4; ++reg) {
          float x2 = acc[mc][nr][reg];                 // already 30*log2e scaled
          int rl = ((const int*)&rlv[mc])[reg];
          bool pos = (rl == kv);
          if (pos) {
            int idx = atomicAdd(&poscnt[row], 1);
            if (idx < 16) posbuf[row * 16 + idx] = x2;
          }
          float xe = (pos || rl == PADMARK) ? NINF : x2;
          s += EXP2R(xe);                              // exp2(-inf)=0
        }
    } else {
      const int sbase = cbl * 128 + wc * 64 + colg * 4;
#pragma unroll
      for (int mc = 0; mc < 4; ++mc)
#pragma unroll
        for (int reg = 0; reg < 4; ++reg) {
          int scol = sbase + mc * 16 + reg;
          float x2 = acc[mc][nr][reg];
          if (scol == kv) target[row] = x2;
          float xe = (scol < NPID) ? x2 : NINF;
          s += EXP2R(xe);
        }
    }
    s += __shfl_xor(s, 16, 64);
    s += __shfl_xor(s, 32, 64);
    if (colg == 0) partials[(size_t)chunk * BT + row] = s;
  }
}

// combine + finalize: per-row losses, block-reduce 5 sums, int64 fixed-point
// atomics (deterministic), last block writes out[0].
__global__ __launch_bounds__(256) void combine(const float* __restrict__ partials,
                                               const float* __restrict__ posbuf,
                                               const int* __restrict__ poscnt,
                                               const float* __restrict__ target,
                                               const float* __restrict__ w2f,
                                               const float* __restrict__ v1f,
                                               const float* __restrict__ fcv,
                                               unsigned long long* __restrict__ ctrl,
                                               float* __restrict__ out) {
  const int tid = threadIdx.x;
  const int row = blockIdx.x * 256 + tid;
  float S = 0.f;
  for (int i = 0; i < 80; ++i) S += partials[(size_t)i * BT + row];
  float lse2n = __log2f(S);                 // base-2 lse of negatives
  int cnt = poscnt[row];
  int cc = cnt < 16 ? cnt : 16;
  float sum = 0.f;
  for (int j = 0; j < cc; ++j) {
    float d = LN2 * (lse2n - posbuf[row * 16 + j]);
    sum += (d > 60.f) ? d : log1pf(__expf(d));
  }
  float w2 = w2f[row];
  float v[5];
  v[0] = fcv[row];
  v[1] = v1f[row];
  v[2] = w2;
  v[3] = w2 * (sum / fmaxf((float)cnt, 1.0f));
  float S2 = 0.f;
  for (int i = 80; i < 160; ++i) S2 += partials[(size_t)i * BT + row];
  v[4] = w2 * LN2 * (__log2f(S2) - target[row]);

#pragma unroll
  for (int k = 0; k < 5; ++k)
#pragma unroll
    for (int d = 1; d < 64; d <<= 1) v[k] += __shfl_xor(v[k], d, 64);
  __shared__ float red[4][5];
  int lane = tid & 63, wv = tid >> 6;
  if (lane == 0)
#pragma unroll
    for (int k = 0; k < 5; ++k) red[wv][k] = v[k];
  __syncthreads();
  if (tid == 0) {
#pragma unroll
    for (int k = 0; k < 5; ++k) {
      double bs = (double)red[0][k] + red[1][k] + red[2][k] + red[3][k];
      long long q = (long long)(bs * FXS + 0.5);
      atomicAdd(&ctrl[k], (unsigned long long)q);
    }
    __threadfence();
    unsigned int prev = atomicAdd((unsigned int*)&ctrl[6], 1u);
    if (prev == (unsigned int)(gridDim.x - 1)) {
      double a[5];
#pragma unroll
      for (int k = 0; k < 5; ++k)
        a[k] = (double)(long long)atomicAdd(&ctrl[k], 0ULL) / FXS;
      double n1 = a[1] > 1.0 ? a[1] : 1.0;
      double n2 = a[2] > 1.0 ? a[2] : 1.0;
      out[0] = (float)(a[0] / (n1 * (double)FDIM) + a[4] / n2 + a[3] / n2);
    }
  }
}

extern "C" void kernel_launch(void* const* d_in, const int* in_sizes, int n_in,
                              void* d_out, int out_size, void* d_ws, size_t ws_size,
                              hipStream_t stream) {
  const float* inputs = (const float*)d_in[0];
  const int*   roi    = (const int*)d_in[1];
  const float* lut    = (const float*)d_in[2];
  const float* reid   = (const float*)d_in[3];
  const int*   rlab   = (const int*)d_in[4];
  float* out = (float*)d_out;

  char* w = (char*)d_ws;
  _Float16* Ap    = (_Float16*)(w);                  // 2,097,152 B
  _Float16* Bp    = (_Float16*)(w + 2097152);        // 5,242,880 B  -> 7,340,032
  float* partials = (float*)(w + 7340032);           // 2,621,440 B  -> 9,961,472
  float* posbuf   = (float*)(w + 9961472);           // 262,144 B    -> 10,223,616
  int*   poscnt   = (int*)(w + 10223616);            // 16,384 B     -> 10,240,000
  float* target   = (float*)(w + 10240000);          // 16,384 B     -> 10,256,384
  int*   g        = (int*)(w + 10256384);            // 16,384 B     -> 10,272,768
  int*   lr       = (int*)(w + 10272768);            // 16,384 B     -> 10,289,152
  float* w2f      = (float*)(w + 10289152);          // 16,384 B     -> 10,305,536
  float* v1f      = (float*)(w + 10305536);          // 16,384 B     -> 10,321,920
  float* fcv      = (float*)(w + 10321920);          // 16,384 B     -> 10,338,304
  unsigned long long* ctrl = (unsigned long long*)(w + 10338304);  // 64 B

  prep<<<2832, 256, 0, stream>>>(inputs, roi, lut, reid, rlab, Ap, Bp,
                                 g, lr, w2f, v1f, fcv, poscnt, ctrl);
  gemm_main<<<2560, 256, 0, stream>>>(Ap, Bp, rlab, g, lr, partials, posbuf, poscnt, target);
  combine<<<BT / 256, 256, 0, stream>>>(partials, posbuf, poscnt, target,
                                        w2f, v1f, fcv, ctrl, out);
}